// Round 1
// baseline (1327.175 us; speedup 1.0000x reference)
//
#include <hip/hip_runtime.h>
#include <hip/hip_bf16.h>

// RelativeAttention: B=2,N=1024,C=512,H=8,HD=64
// Round 0: all-fp32 correctness baseline.
//  K1 (x3): qkv projections, tiled GEMM, scatter to [B,H,N,HD], SCALE folded into qh
//  K2     : fused per-(b,i) attention: S = qh.(kh+rpb) + pair ; p=exp(S);
//           acc = sum_j p_j*(vh+rpb) ; x[b,i,h,c] = acc / sum(p)
//  K3     : out = x @ Wp + bp
// ws: qh(4MB) kh(4MB) vh(4MB) x(4MB) = 16MB

#define NB 2
#define NN 1024
#define NC 512
#define NH 8
#define NHD 64

// ---------------------------------------------------------------------------
// Tiled fp32 GEMM: Y = X[M,512] @ W[512,512]  (M = 2048)
// MODE 0: scatter to [B,H,N,HD] with scale (proj).  MODE 1: Y[M,512] + bias.
// grid (M/64, 512/64), block 256 (16x16 threads, 4x4 micro-tile)
// ---------------------------------------------------------------------------
template <int MODE>
__global__ __launch_bounds__(256) void gemm512(
    const float* __restrict__ X, const float* __restrict__ W,
    const float* __restrict__ bias, float* __restrict__ Y, float scale)
{
    __shared__ float As[32][68];   // [k][m], padded
    __shared__ float Bs[32][68];   // [k][n], padded
    const int t  = threadIdx.x;
    const int tx = t & 15, ty = t >> 4;
    const int m0 = blockIdx.x * 64;
    const int n0 = blockIdx.y * 64;

    float acc[4][4] = {};

    for (int k0 = 0; k0 < 512; k0 += 32) {
        // A tile 64x32 -> As[k][m] (transposed store)
        #pragma unroll
        for (int l = 0; l < 2; l++) {
            int qi = t + l * 256;
            int r = qi >> 3, q = qi & 7;
            float4 av = *reinterpret_cast<const float4*>(
                X + (size_t)(m0 + r) * 512 + k0 + q * 4);
            As[q * 4 + 0][r] = av.x;
            As[q * 4 + 1][r] = av.y;
            As[q * 4 + 2][r] = av.z;
            As[q * 4 + 3][r] = av.w;
        }
        // B tile 32x64 -> Bs[k][n]
        #pragma unroll
        for (int l = 0; l < 2; l++) {
            int qi = t + l * 256;
            int kk = qi >> 4, q = qi & 15;
            *reinterpret_cast<float4*>(&Bs[kk][q * 4]) =
                *reinterpret_cast<const float4*>(
                    W + (size_t)(k0 + kk) * 512 + n0 + q * 4);
        }
        __syncthreads();
        #pragma unroll
        for (int kk = 0; kk < 32; kk++) {
            float4 a4 = *reinterpret_cast<const float4*>(&As[kk][ty * 4]);
            float4 b4 = *reinterpret_cast<const float4*>(&Bs[kk][tx * 4]);
            float av[4] = {a4.x, a4.y, a4.z, a4.w};
            float bv[4] = {b4.x, b4.y, b4.z, b4.w};
            #pragma unroll
            for (int ii = 0; ii < 4; ii++)
                #pragma unroll
                for (int jj = 0; jj < 4; jj++)
                    acc[ii][jj] = fmaf(av[ii], bv[jj], acc[ii][jj]);
        }
        __syncthreads();
    }

    if (MODE == 0) {
        // scatter: Y[((b*8+h)*1024+n)*64 + d] = acc*scale ; h = n0>>6 (BN==HD)
        const int h = n0 >> 6;
        #pragma unroll
        for (int ii = 0; ii < 4; ii++) {
            int m = m0 + ty * 4 + ii;
            int bb = m >> 10, nn = m & 1023;
            float4 o;
            o.x = acc[ii][0] * scale;
            o.y = acc[ii][1] * scale;
            o.z = acc[ii][2] * scale;
            o.w = acc[ii][3] * scale;
            *reinterpret_cast<float4*>(
                Y + ((size_t)((bb * 8 + h) * 1024 + nn)) * 64 + tx * 4) = o;
        }
    } else {
        float4 bv = *reinterpret_cast<const float4*>(bias + n0 + tx * 4);
        #pragma unroll
        for (int ii = 0; ii < 4; ii++) {
            int m = m0 + ty * 4 + ii;
            float4 o;
            o.x = acc[ii][0] + bv.x;
            o.y = acc[ii][1] + bv.y;
            o.z = acc[ii][2] + bv.z;
            o.w = acc[ii][3] + bv.w;
            *reinterpret_cast<float4*>(Y + (size_t)m * 512 + n0 + tx * 4) = o;
        }
    }
}

// ---------------------------------------------------------------------------
// Fused attention, one block per (b,i), 512 threads = 8 waves (wave = head).
// Score phase: lane <-> j (tile of 64 j); accum phase: quarter-wave, lane ->
// (g = j-subrange, l16 -> 4 consecutive c).
// ---------------------------------------------------------------------------
__global__ __launch_bounds__(512) void attn_fused(
    const float* __restrict__ qh, const float* __restrict__ kh,
    const float* __restrict__ vh, const float* __restrict__ rpb,
    const float* __restrict__ mask, float* __restrict__ x)
{
    const int bid = blockIdx.x;
    const int b = bid >> 10, i = bid & 1023;
    const int t = threadIdx.x;
    const int w = t >> 6;          // head
    const int lane = t & 63;
    const int g = lane >> 4, l16 = lane & 15;

    __shared__ float q_s[512];
    q_s[t] = qh[((size_t)(b * 8 + w) * 1024 + i) * 64 + lane];
    __syncthreads();

    float qr[64];
    #pragma unroll
    for (int c = 0; c < 64; c++) qr[c] = q_s[w * 64 + c];

    const float mi = mask[b * 1024 + i];
    const float* khb  = kh  + (size_t)(b * 8 + w) * 1024 * 64;
    const float* vhb  = vh  + (size_t)(b * 8 + w) * 1024 * 64;
    const float* rpbb = rpb + (size_t)(b * 1024 + i) * 1024 * 64;

    float lsum = 0.0f;
    float accx = 0.0f, accy = 0.0f, accz = 0.0f, accw = 0.0f;

    for (int j0 = 0; j0 < 1024; j0 += 64) {
        // ---- score for j = j0 + lane ----
        float mj = mask[b * 1024 + j0 + lane];
        float mx = fmaxf(mi, mj);
        float s = (mx < 0.0f) ? 0.0f : fminf(mi, mj);  // pairwise mask term
        const float4* kr = reinterpret_cast<const float4*>(
            khb + (size_t)(j0 + lane) * 64);
        const float4* rr = reinterpret_cast<const float4*>(
            rpbb + (size_t)(j0 + lane) * 64);
        #pragma unroll
        for (int c4 = 0; c4 < 16; c4++) {
            float4 kv = kr[c4];
            float4 rv = rr[c4];
            s = fmaf(qr[c4 * 4 + 0], kv.x + rv.x, s);
            s = fmaf(qr[c4 * 4 + 1], kv.y + rv.y, s);
            s = fmaf(qr[c4 * 4 + 2], kv.z + rv.z, s);
            s = fmaf(qr[c4 * 4 + 3], kv.w + rv.w, s);
        }
        float p = __expf(s);   // logits bounded ~|6|; masked -> exp(-1e4) = 0
        lsum += p;

        // ---- accumulate: acc[c] += p_j * (vh[j][c] + rpb[j][c]) ----
        const float4* vrow = reinterpret_cast<const float4*>(vhb + (size_t)j0 * 64);
        const float4* rrow = reinterpret_cast<const float4*>(rpbb + (size_t)j0 * 64);
        #pragma unroll
        for (int it = 0; it < 16; it++) {
            int j = g * 16 + it;            // this group's j within tile
            float pj = __shfl(p, j, 64);
            float4 vv = vrow[j * 16 + l16];
            float4 rv2 = rrow[j * 16 + l16];
            accx = fmaf(pj, vv.x + rv2.x, accx);
            accy = fmaf(pj, vv.y + rv2.y, accy);
            accz = fmaf(pj, vv.z + rv2.z, accz);
            accw = fmaf(pj, vv.w + rv2.w, accw);
        }
    }

    // row sum of p across all 64 lanes (each lane saw distinct j's)
    #pragma unroll
    for (int o = 32; o > 0; o >>= 1) lsum += __shfl_xor(lsum, o, 64);
    // sum partial accumulators across the 4 j-groups (lane bits 4,5)
    accx += __shfl_xor(accx, 16, 64); accx += __shfl_xor(accx, 32, 64);
    accy += __shfl_xor(accy, 16, 64); accy += __shfl_xor(accy, 32, 64);
    accz += __shfl_xor(accz, 16, 64); accz += __shfl_xor(accz, 32, 64);
    accw += __shfl_xor(accw, 16, 64); accw += __shfl_xor(accw, 32, 64);

    float inv = 1.0f / lsum;
    if (g == 0) {
        float4 o;
        o.x = accx * inv; o.y = accy * inv; o.z = accz * inv; o.w = accw * inv;
        *reinterpret_cast<float4*>(
            x + (size_t)(b * 1024 + i) * 512 + w * 64 + l16 * 4) = o;
    }
}

// ---------------------------------------------------------------------------
extern "C" void kernel_launch(void* const* d_in, const int* in_sizes, int n_in,
                              void* d_out, int out_size, void* d_ws, size_t ws_size,
                              hipStream_t stream)
{
    (void)in_sizes; (void)n_in; (void)out_size; (void)ws_size;
    const float* q    = (const float*)d_in[0];
    const float* k    = (const float*)d_in[1];
    const float* v    = (const float*)d_in[2];
    const float* rpb  = (const float*)d_in[3];
    const float* mask = (const float*)d_in[4];
    const float* Wq   = (const float*)d_in[5];
    const float* Wk   = (const float*)d_in[6];
    const float* Wv   = (const float*)d_in[7];
    const float* Wp   = (const float*)d_in[8];
    const float* bp   = (const float*)d_in[9];
    float* out = (float*)d_out;

    float* qh = (float*)d_ws;            // [B,H,N,HD] 1M floats
    float* kh = qh + 1048576;
    float* vh = kh + 1048576;
    float* xb = vh + 1048576;            // [B,N,C]

    const float SCALE = 0.125f;          // HD^-0.5, folded into qh

    dim3 gg(32, 8, 1);                   // M/64=32, 512/64=8
    gemm512<0><<<gg, 256, 0, stream>>>(q, Wq, nullptr, qh, SCALE);
    gemm512<0><<<gg, 256, 0, stream>>>(k, Wk, nullptr, kh, 1.0f);
    gemm512<0><<<gg, 256, 0, stream>>>(v, Wv, nullptr, vh, 1.0f);

    attn_fused<<<2048, 512, 0, stream>>>(qh, kh, vh, rpb, mask, xb);

    gemm512<1><<<gg, 256, 0, stream>>>(xb, Wp, bp, out, 1.0f);
}

// Round 2
// 345.341 us; speedup vs baseline: 3.8431x; 3.8431x over previous
//
#include <hip/hip_runtime.h>
#include <hip/hip_bf16.h>

// RelativeAttention B=2,N=1024,C=512,H=8,HD=64 — round 1: MFMA restructure.
//  gemm512<0> x2 : q,k projections -> bf16 [b,h,n,64] (SCALE folded into q)
//  gemm512<2>    : v projection -> bf16 TRANSPOSED [b,h,64c,1024n] (LDS transpose)
//  attn_mfma     : block=(b, i-tile16, jsplit4); 8 waves=8 heads.
//                  per 32-j tile: rpb->LDS bf16 (read once from HBM);
//                  S1=QK^T (MFMA, kh frags from global); S2=q.rpb (MFMA, heads as M);
//                  P=exp(S1+S2+pairmask) (no max: logits bounded, exp(-1e4)->0);
//                  X1=P@vhT (MFMA); X2=P@rpb (VALU, lane=(h,c8)).
//                  unnormalized partials + lsum -> ws (exact combine across jsplits)
//  combine       : xb = sum_js xpart / sum_js lsum
//  gemm512<1>    : out = xb @ Wp + bp
// ws: qh 2MB | kh 2MB | vhT 2MB | xpart 16MB | lsum 256KB | xb 4MB = 26.3MB

typedef __attribute__((ext_vector_type(8))) short short8;
typedef __attribute__((ext_vector_type(4))) float f32x4;

__device__ __forceinline__ unsigned short f2b(float f) {
    union { float f; unsigned u; } v; v.f = f;
    unsigned r = (v.u + 0x7FFF + ((v.u >> 16) & 1)) >> 16;   // RNE
    return (unsigned short)r;
}
__device__ __forceinline__ float b2f(unsigned short h) {
    union { unsigned u; float f; } v; v.u = ((unsigned)h) << 16;
    return v.f;
}

// ---------------------------------------------------------------------------
// GEMM: Y = X[2048,512] @ W[512,512]
// MODE 0: bf16 scatter [b,h,n,64]*scale   MODE 1: f32 [m,512]+bias
// MODE 2: bf16 transposed scatter [b,h,64c,1024n] via LDS tile transpose
// ---------------------------------------------------------------------------
template <int MODE>
__global__ __launch_bounds__(256) void gemm512(
    const float* __restrict__ X, const float* __restrict__ W,
    const float* __restrict__ bias, float* __restrict__ Yf,
    unsigned short* __restrict__ Ybf, float scale)
{
    __shared__ float As[32][68];
    __shared__ float Bs[32][68];
    __shared__ float Ts[(MODE == 2) ? 64 : 1][65];
    const int t  = threadIdx.x;
    const int tx = t & 15, ty = t >> 4;
    const int m0 = blockIdx.x * 64;
    const int n0 = blockIdx.y * 64;

    float acc[4][4] = {};

    for (int k0 = 0; k0 < 512; k0 += 32) {
        #pragma unroll
        for (int l = 0; l < 2; l++) {
            int qi = t + l * 256;
            int r = qi >> 3, q = qi & 7;
            float4 av = *reinterpret_cast<const float4*>(
                X + (size_t)(m0 + r) * 512 + k0 + q * 4);
            As[q * 4 + 0][r] = av.x; As[q * 4 + 1][r] = av.y;
            As[q * 4 + 2][r] = av.z; As[q * 4 + 3][r] = av.w;
        }
        #pragma unroll
        for (int l = 0; l < 2; l++) {
            int qi = t + l * 256;
            int kk = qi >> 4, q = qi & 15;
            *reinterpret_cast<float4*>(&Bs[kk][q * 4]) =
                *reinterpret_cast<const float4*>(
                    W + (size_t)(k0 + kk) * 512 + n0 + q * 4);
        }
        __syncthreads();
        #pragma unroll
        for (int kk = 0; kk < 32; kk++) {
            float4 a4 = *reinterpret_cast<const float4*>(&As[kk][ty * 4]);
            float4 b4 = *reinterpret_cast<const float4*>(&Bs[kk][tx * 4]);
            float av[4] = {a4.x, a4.y, a4.z, a4.w};
            float bv[4] = {b4.x, b4.y, b4.z, b4.w};
            #pragma unroll
            for (int ii = 0; ii < 4; ii++)
                #pragma unroll
                for (int jj = 0; jj < 4; jj++)
                    acc[ii][jj] = fmaf(av[ii], bv[jj], acc[ii][jj]);
        }
        __syncthreads();
    }

    if (MODE == 0) {
        const int h = n0 >> 6;
        #pragma unroll
        for (int ii = 0; ii < 4; ii++) {
            int m = m0 + ty * 4 + ii;
            int bb = m >> 10, nn = m & 1023;
            ushort4 o;
            o.x = f2b(acc[ii][0] * scale); o.y = f2b(acc[ii][1] * scale);
            o.z = f2b(acc[ii][2] * scale); o.w = f2b(acc[ii][3] * scale);
            *reinterpret_cast<ushort4*>(
                Ybf + ((size_t)((bb * 8 + h) * 1024 + nn)) * 64 + tx * 4) = o;
        }
    } else if (MODE == 1) {
        float4 bv = *reinterpret_cast<const float4*>(bias + n0 + tx * 4);
        #pragma unroll
        for (int ii = 0; ii < 4; ii++) {
            int m = m0 + ty * 4 + ii;
            float4 o;
            o.x = acc[ii][0] + bv.x; o.y = acc[ii][1] + bv.y;
            o.z = acc[ii][2] + bv.z; o.w = acc[ii][3] + bv.w;
            *reinterpret_cast<float4*>(Yf + (size_t)m * 512 + n0 + tx * 4) = o;
        }
    } else {
        // transpose via LDS: Ts[m_local][n_local] then write [b,h,c,n]
        #pragma unroll
        for (int ii = 0; ii < 4; ii++)
            #pragma unroll
            for (int jj = 0; jj < 4; jj++)
                Ts[ty * 4 + ii][tx * 4 + jj] = acc[ii][jj];
        __syncthreads();
        const int h = n0 >> 6;
        const int bb = m0 >> 10, nn = m0 & 1023;
        const int rc = t >> 2, jc = t & 3;        // rc = c-row 0..63, jc = 16-token chunk
        unsigned short tmp[16];
        #pragma unroll
        for (int q = 0; q < 16; q++) tmp[q] = f2b(Ts[jc * 16 + q][rc]);
        unsigned short* dst = Ybf + (((size_t)(bb * 8 + h) * 64 + rc) << 10) + nn + jc * 16;
        *reinterpret_cast<short8*>(dst)     = *reinterpret_cast<short8*>(&tmp[0]);
        *reinterpret_cast<short8*>(dst + 8) = *reinterpret_cast<short8*>(&tmp[8]);
    }
}

// ---------------------------------------------------------------------------
// attn: grid 512 = b(2) x itile(64) x jsplit(4); 512 threads = 8 waves = heads
// ---------------------------------------------------------------------------
__global__ __launch_bounds__(512) void attn_mfma(
    const unsigned short* __restrict__ qhg, const unsigned short* __restrict__ khg,
    const unsigned short* __restrict__ vtg, const float* __restrict__ rpb,
    const float* __restrict__ mask, float* __restrict__ xpart,
    float* __restrict__ lsump)
{
    __shared__ unsigned short q1[8][16][72];     // [h][i][c]  (c padded 64->72)
    __shared__ unsigned short rpb_s[16][32][72]; // [i][j][c]
    __shared__ unsigned short P[8][16][40];      // [h][i][j]  (j padded 32->40)
    __shared__ float S2s[16][8][32];             // [i][h][j]
    __shared__ float mj_s[32];

    const int bid = blockIdx.x;
    const int js = bid & 3, it = (bid >> 2) & 63, b = bid >> 8;
    const int i0 = it * 16, jb = js * 256;
    const int t = threadIdx.x, w = t >> 6, l = t & 63;
    const int lg = l >> 4, l16 = l & 15;

    // stage q tile: [8h][16i][64c] bf16
    {
        int h = t >> 6, i = (t >> 2) & 15, c = (t & 3) * 16;
        const short8* src = reinterpret_cast<const short8*>(
            qhg + (((size_t)(b * 8 + h) * 1024 + i0 + i) << 6) + c);
        *reinterpret_cast<short8*>(&q1[h][i][c])     = src[0];
        *reinterpret_cast<short8*>(&q1[h][i][c + 8]) = src[1];
    }

    float mrow[4];
    #pragma unroll
    for (int r = 0; r < 4; r++) mrow[r] = mask[b * 1024 + i0 + lg * 4 + r];

    f32x4 x1[4];
    #pragma unroll
    for (int cs = 0; cs < 4; cs++) x1[cs] = 0.0f;
    float lsum[4] = {0.f, 0.f, 0.f, 0.f};
    float X2a[2][8];
    #pragma unroll
    for (int il = 0; il < 2; il++)
        #pragma unroll
        for (int cc = 0; cc < 8; cc++) X2a[il][cc] = 0.f;

    const unsigned short* khb = khg + ((size_t)(b * 8 + w) << 16);
    const unsigned short* vtb = vtg + ((size_t)(b * 8 + w) << 16);
    const int xh = l >> 3, xc = l & 7;   // X2 lane mapping: (head, c-chunk)

    for (int jt = 0; jt < 8; ++jt) {
        const int j0 = jb + jt * 32;
        __syncthreads();                               // barA: prev readers done
        // ---- stage rpb tile [16i][32j][64c] f32 -> bf16 ----
        #pragma unroll
        for (int itr = 0; itr < 8; ++itr) {
            int flat = (itr * 512 + t) * 8;
            int i = flat >> 11, j = (flat >> 6) & 31, c = flat & 63;
            const float4* s = reinterpret_cast<const float4*>(
                rpb + ((((size_t)(b * 1024 + i0 + i)) * 1024 + j0 + j) << 6) + c);
            float4 ua = s[0], ub = s[1];
            short8 pk;
            pk[0] = (short)f2b(ua.x); pk[1] = (short)f2b(ua.y);
            pk[2] = (short)f2b(ua.z); pk[3] = (short)f2b(ua.w);
            pk[4] = (short)f2b(ub.x); pk[5] = (short)f2b(ub.y);
            pk[6] = (short)f2b(ub.z); pk[7] = (short)f2b(ub.w);
            *reinterpret_cast<short8*>(&rpb_s[i][j][c]) = pk;
        }
        if (t < 32) mj_s[t] = mask[b * 1024 + j0 + t];
        __syncthreads();                               // barB: tile staged

        // ---- S1 = QK^T : D[16i x 16j] x 2 jsub, K=64 (2 mfma-K steps) ----
        f32x4 C1[2]; C1[0] = 0.0f; C1[1] = 0.0f;
        short8 a1[2];
        a1[0] = *reinterpret_cast<const short8*>(&q1[w][l16][8 * lg]);
        a1[1] = *reinterpret_cast<const short8*>(&q1[w][l16][32 + 8 * lg]);
        #pragma unroll
        for (int ch = 0; ch < 2; ++ch) {
            #pragma unroll
            for (int jsub = 0; jsub < 2; ++jsub) {
                short8 kb = *reinterpret_cast<const short8*>(
                    khb + (((size_t)(j0 + jsub * 16 + l16)) << 6) + ch * 32 + 8 * lg);
                C1[jsub] = __builtin_amdgcn_mfma_f32_16x16x32_bf16(a1[ch], kb, C1[jsub], 0, 0, 0);
            }
        }
        // ---- S2 = q.rpb : per local i (wave w owns i=2w,2w+1), M=heads ----
        #pragma unroll
        for (int il = 0; il < 2; ++il) {
            int i = 2 * w + il;
            f32x4 D2[2]; D2[0] = 0.0f; D2[1] = 0.0f;
            #pragma unroll
            for (int ch = 0; ch < 2; ++ch) {
                short8 a2 = *reinterpret_cast<const short8*>(
                    &q1[l16 & 7][i][ch * 32 + 8 * lg]);   // rows 8-15 dup of 0-7 (ignored)
                #pragma unroll
                for (int jsub = 0; jsub < 2; ++jsub) {
                    short8 b2 = *reinterpret_cast<const short8*>(
                        &rpb_s[i][jsub * 16 + l16][ch * 32 + 8 * lg]);
                    D2[jsub] = __builtin_amdgcn_mfma_f32_16x16x32_bf16(a2, b2, D2[jsub], 0, 0, 0);
                }
            }
            if (l < 32) {   // D rows 0..7 = valid heads
                #pragma unroll
                for (int jsub = 0; jsub < 2; ++jsub)
                    #pragma unroll
                    for (int r = 0; r < 4; ++r)
                        S2s[i][lg * 4 + r][jsub * 16 + l16] = D2[jsub][r];
            }
        }
        __syncthreads();                               // barC: S2 ready

        // ---- P = exp(S1 + S2 + pairmask), write bf16 P_lds, accum lsum ----
        #pragma unroll
        for (int jsub = 0; jsub < 2; ++jsub) {
            float mj = mj_s[jsub * 16 + l16];
            #pragma unroll
            for (int r = 0; r < 4; ++r) {
                int ir = lg * 4 + r;
                float mi = mrow[r];
                float pm = (fmaxf(mi, mj) < 0.f) ? 0.f : fminf(mi, mj);
                float s = C1[jsub][r] + S2s[ir][w][jsub * 16 + l16] + pm;
                float p = __expf(s);                   // bounded logits; -1e4 -> 0
                lsum[r] += p;
                P[w][ir][jsub * 16 + l16] = f2b(p);
            }
        }
        __syncthreads();                               // barD: P ready

        // ---- X1 += P @ vhT : D[16i x 64c] ----
        short8 pa = *reinterpret_cast<const short8*>(&P[w][l16][8 * lg]);
        #pragma unroll
        for (int cs = 0; cs < 4; ++cs) {
            short8 vb = *reinterpret_cast<const short8*>(
                vtb + ((size_t)(cs * 16 + l16) << 10) + j0 + 8 * lg);
            x1[cs] = __builtin_amdgcn_mfma_f32_16x16x32_bf16(pa, vb, x1[cs], 0, 0, 0);
        }
        // ---- X2 += P @ rpb (VALU): lane=(head xh, c-chunk xc) ----
        #pragma unroll
        for (int il = 0; il < 2; ++il) {
            int i = 2 * w + il;
            for (int j = 0; j < 32; ++j) {
                float p = b2f(P[xh][i][j]);
                short8 rv8 = *reinterpret_cast<const short8*>(&rpb_s[i][j][xc * 8]);
                #pragma unroll
                for (int cc = 0; cc < 8; ++cc)
                    X2a[il][cc] = fmaf(p, b2f((unsigned short)rv8[cc]), X2a[il][cc]);
            }
        }
    }

    // reduce lsum over the 16 j-lanes
    #pragma unroll
    for (int r = 0; r < 4; ++r) {
        float v = lsum[r];
        v += __shfl_xor(v, 1, 64); v += __shfl_xor(v, 2, 64);
        v += __shfl_xor(v, 4, 64); v += __shfl_xor(v, 8, 64);
        lsum[r] = v;
    }

    __syncthreads();   // all X2/rpb_s reads done; reuse rpb_s as x2 buffer
    float* x2s = reinterpret_cast<float*>(&rpb_s[0][0][0]);   // [16i][8h][64c]
    #pragma unroll
    for (int il = 0; il < 2; ++il) {
        float4 v0, v1;
        v0.x = X2a[il][0]; v0.y = X2a[il][1]; v0.z = X2a[il][2]; v0.w = X2a[il][3];
        v1.x = X2a[il][4]; v1.y = X2a[il][5]; v1.z = X2a[il][6]; v1.w = X2a[il][7];
        float* d = &x2s[((2 * w + il) * 8 + xh) * 64 + xc * 8];
        *reinterpret_cast<float4*>(d)     = v0;
        *reinterpret_cast<float4*>(d + 4) = v1;
    }
    __syncthreads();

    // output: unnormalized x1+x2 partials and lsum per jsplit
    #pragma unroll
    for (int cs = 0; cs < 4; ++cs)
        #pragma unroll
        for (int r = 0; r < 4; ++r) {
            int ir = lg * 4 + r;
            float val = x1[cs][r] + x2s[(ir * 8 + w) * 64 + cs * 16 + l16];
            xpart[(((size_t)js << 20)) + ((size_t)(b * 1024 + i0 + ir)) * 512
                  + w * 64 + cs * 16 + l16] = val;
        }
    if (l16 == 0) {
        #pragma unroll
        for (int r = 0; r < 4; ++r)
            lsump[((size_t)js << 14) + (b * 8 + w) * 1024 + i0 + lg * 4 + r] = lsum[r];
    }
}

// ---------------------------------------------------------------------------
__global__ __launch_bounds__(256) void combine(
    const float* __restrict__ xpart, const float* __restrict__ lsump,
    float* __restrict__ xb)
{
    int idx4 = blockIdx.x * 256 + threadIdx.x;     // 262144 threads x float4
    size_t base = (size_t)idx4 * 4;
    int row = (int)(base >> 9), col = (int)(base & 511);
    int bb = row >> 10, n = row & 1023, h = col >> 6;
    float ax = 0.f, ay = 0.f, az = 0.f, aw = 0.f, ls = 0.f;
    #pragma unroll
    for (int js = 0; js < 4; ++js) {
        float4 v = *reinterpret_cast<const float4*>(xpart + ((size_t)js << 20) + base);
        ax += v.x; ay += v.y; az += v.z; aw += v.w;
        ls += lsump[(js << 14) + (bb * 8 + h) * 1024 + n];
    }
    float inv = 1.f / ls;
    float4 o; o.x = ax * inv; o.y = ay * inv; o.z = az * inv; o.w = aw * inv;
    *reinterpret_cast<float4*>(xb + base) = o;
}

// ---------------------------------------------------------------------------
extern "C" void kernel_launch(void* const* d_in, const int* in_sizes, int n_in,
                              void* d_out, int out_size, void* d_ws, size_t ws_size,
                              hipStream_t stream)
{
    (void)in_sizes; (void)n_in; (void)out_size; (void)ws_size;
    const float* q    = (const float*)d_in[0];
    const float* k    = (const float*)d_in[1];
    const float* v    = (const float*)d_in[2];
    const float* rpb  = (const float*)d_in[3];
    const float* mask = (const float*)d_in[4];
    const float* Wq   = (const float*)d_in[5];
    const float* Wk   = (const float*)d_in[6];
    const float* Wv   = (const float*)d_in[7];
    const float* Wp   = (const float*)d_in[8];
    const float* bp   = (const float*)d_in[9];
    float* out = (float*)d_out;

    unsigned short* qhb = (unsigned short*)d_ws;     // bf16 [2,8,1024,64]
    unsigned short* khb = qhb + 1048576;
    unsigned short* vtb = khb + 1048576;             // bf16 [2,8,64,1024]
    float* xpart = (float*)(vtb + 1048576);          // [4][2048][512]
    float* lsump = xpart + 4194304;                  // [4][16][1024]
    float* xb    = lsump + 65536;                    // [2048][512]

    dim3 gg(32, 8, 1);
    gemm512<0><<<gg, 256, 0, stream>>>(q, Wq, nullptr, nullptr, qhb, 0.125f);
    gemm512<0><<<gg, 256, 0, stream>>>(k, Wk, nullptr, nullptr, khb, 1.0f);
    gemm512<2><<<gg, 256, 0, stream>>>(v, Wv, nullptr, nullptr, vtb, 1.0f);

    attn_mfma<<<512, 512, 0, stream>>>(qhb, khb, vtb, rpb, mask, xpart, lsump);

    combine<<<1024, 256, 0, stream>>>(xpart, lsump, xb);

    gemm512<1><<<gg, 256, 0, stream>>>(xb, Wp, bp, out, nullptr, 1.0f);
}

// Round 3
// 273.655 us; speedup vs baseline: 4.8498x; 1.2620x over previous
//
#include <hip/hip_runtime.h>
#include <hip/hip_bf16.h>

// RelativeAttention B=2,N=1024,C=512,H=8,HD=64 — round 2: HBM-streaming attn.
//  gemm512<0> x2 : q,k projections -> bf16 [b,h,n,64] (SCALE folded into q)
//  gemm512<2>    : v projection -> bf16 TRANSPOSED [b,h,64c,1024n]
//  attn_mfma     : block=(b, i-tile16, jsplit2) = 256 blocks (1/CU); 8 waves=8 heads.
//                  T14 prefetch: next rpb tile in 64 VGPRs during compute.
//                  S1=QK^T (MFMA); S2^T=rpb(A)@q(B) (MFMA, all-contig frags);
//                  P=exp(S1+S2+pairmask); X1=P@vhT (MFMA);
//                  X2=P(A)@rpb(B) MFMA, B-frags via 8x ds_read_u16 gather.
//                  unnormalized partials + lsum -> ws; exact combine across jsplits.
//  combine       : xb = sum_js xpart / sum_js lsum
//  gemm512<1>    : out = xb @ Wp + bp
// ws: qh 2MB | kh 2MB | vhT 2MB | xpart 8MB | lsum 128KB | xb 4MB

typedef __attribute__((ext_vector_type(8))) short short8;
typedef __attribute__((ext_vector_type(4))) float f32x4;

__device__ __forceinline__ unsigned short f2b(float f) {
    union { float f; unsigned u; } v; v.f = f;
    unsigned r = (v.u + 0x7FFF + ((v.u >> 16) & 1)) >> 16;   // RNE
    return (unsigned short)r;
}
__device__ __forceinline__ float b2f(unsigned short h) {
    union { unsigned u; float f; } v; v.u = ((unsigned)h) << 16;
    return v.f;
}

// ---------------------------------------------------------------------------
// GEMM: Y = X[2048,512] @ W[512,512]
// MODE 0: bf16 scatter [b,h,n,64]*scale   MODE 1: f32 [m,512]+bias
// MODE 2: bf16 transposed scatter [b,h,64c,1024n] via LDS tile transpose
// ---------------------------------------------------------------------------
template <int MODE>
__global__ __launch_bounds__(256) void gemm512(
    const float* __restrict__ X, const float* __restrict__ W,
    const float* __restrict__ bias, float* __restrict__ Yf,
    unsigned short* __restrict__ Ybf, float scale)
{
    __shared__ float As[32][68];
    __shared__ float Bs[32][68];
    __shared__ float Ts[(MODE == 2) ? 64 : 1][65];
    const int t  = threadIdx.x;
    const int tx = t & 15, ty = t >> 4;
    const int m0 = blockIdx.x * 64;
    const int n0 = blockIdx.y * 64;

    float acc[4][4] = {};

    for (int k0 = 0; k0 < 512; k0 += 32) {
        #pragma unroll
        for (int l = 0; l < 2; l++) {
            int qi = t + l * 256;
            int r = qi >> 3, q = qi & 7;
            float4 av = *reinterpret_cast<const float4*>(
                X + (size_t)(m0 + r) * 512 + k0 + q * 4);
            As[q * 4 + 0][r] = av.x; As[q * 4 + 1][r] = av.y;
            As[q * 4 + 2][r] = av.z; As[q * 4 + 3][r] = av.w;
        }
        #pragma unroll
        for (int l = 0; l < 2; l++) {
            int qi = t + l * 256;
            int kk = qi >> 4, q = qi & 15;
            *reinterpret_cast<float4*>(&Bs[kk][q * 4]) =
                *reinterpret_cast<const float4*>(
                    W + (size_t)(k0 + kk) * 512 + n0 + q * 4);
        }
        __syncthreads();
        #pragma unroll
        for (int kk = 0; kk < 32; kk++) {
            float4 a4 = *reinterpret_cast<const float4*>(&As[kk][ty * 4]);
            float4 b4 = *reinterpret_cast<const float4*>(&Bs[kk][tx * 4]);
            float av[4] = {a4.x, a4.y, a4.z, a4.w};
            float bv[4] = {b4.x, b4.y, b4.z, b4.w};
            #pragma unroll
            for (int ii = 0; ii < 4; ii++)
                #pragma unroll
                for (int jj = 0; jj < 4; jj++)
                    acc[ii][jj] = fmaf(av[ii], bv[jj], acc[ii][jj]);
        }
        __syncthreads();
    }

    if (MODE == 0) {
        const int h = n0 >> 6;
        #pragma unroll
        for (int ii = 0; ii < 4; ii++) {
            int m = m0 + ty * 4 + ii;
            int bb = m >> 10, nn = m & 1023;
            ushort4 o;
            o.x = f2b(acc[ii][0] * scale); o.y = f2b(acc[ii][1] * scale);
            o.z = f2b(acc[ii][2] * scale); o.w = f2b(acc[ii][3] * scale);
            *reinterpret_cast<ushort4*>(
                Ybf + ((size_t)((bb * 8 + h) * 1024 + nn)) * 64 + tx * 4) = o;
        }
    } else if (MODE == 1) {
        float4 bv = *reinterpret_cast<const float4*>(bias + n0 + tx * 4);
        #pragma unroll
        for (int ii = 0; ii < 4; ii++) {
            int m = m0 + ty * 4 + ii;
            float4 o;
            o.x = acc[ii][0] + bv.x; o.y = acc[ii][1] + bv.y;
            o.z = acc[ii][2] + bv.z; o.w = acc[ii][3] + bv.w;
            *reinterpret_cast<float4*>(Yf + (size_t)m * 512 + n0 + tx * 4) = o;
        }
    } else {
        #pragma unroll
        for (int ii = 0; ii < 4; ii++)
            #pragma unroll
            for (int jj = 0; jj < 4; jj++)
                Ts[ty * 4 + ii][tx * 4 + jj] = acc[ii][jj];
        __syncthreads();
        const int h = n0 >> 6;
        const int bb = m0 >> 10, nn = m0 & 1023;
        const int rc = t >> 2, jc = t & 3;
        unsigned short tmp[16];
        #pragma unroll
        for (int q = 0; q < 16; q++) tmp[q] = f2b(Ts[jc * 16 + q][rc]);
        unsigned short* dst = Ybf + (((size_t)(bb * 8 + h) * 64 + rc) << 10) + nn + jc * 16;
        *reinterpret_cast<short8*>(dst)     = *reinterpret_cast<short8*>(&tmp[0]);
        *reinterpret_cast<short8*>(dst + 8) = *reinterpret_cast<short8*>(&tmp[8]);
    }
}

// ---------------------------------------------------------------------------
// prefetch helper: issue next 32-j rpb tile (f32) into 64 VGPRs
// ---------------------------------------------------------------------------
__device__ __forceinline__ void issue_rpb(const float* __restrict__ rpbb,
                                          int j0, int t, float4 (&pf)[16]) {
    #pragma unroll
    for (int itr = 0; itr < 8; ++itr) {
        int flat = (itr * 512 + t) * 8;
        int i = flat >> 11, j = (flat >> 6) & 31, c = flat & 63;
        const float4* s = reinterpret_cast<const float4*>(
            rpbb + ((size_t)i * 1024 + j0 + j) * 64 + c);
        pf[itr * 2]     = s[0];
        pf[itr * 2 + 1] = s[1];
    }
}

// ---------------------------------------------------------------------------
// attn: grid 256 = b(2) x itile(64) x jsplit(2); 512 threads = 8 waves = heads
// ---------------------------------------------------------------------------
__global__ __launch_bounds__(512) void attn_mfma(
    const unsigned short* __restrict__ qhg, const unsigned short* __restrict__ khg,
    const unsigned short* __restrict__ vtg, const float* __restrict__ rpb,
    const float* __restrict__ mask, float* __restrict__ xpart,
    float* __restrict__ lsump)
{
    __shared__ unsigned short q1[8][16][72];     // [h][i][c]
    __shared__ unsigned short rpb_s[16][32][72]; // [i][j][c] (pad 72)
    __shared__ unsigned short P[8][17][40];      // [h][i][j] (i,j padded)
    __shared__ float S2s[16][8][33];             // [i][h][j] (pad 33)
    __shared__ float mj_s[32];

    const int bid = blockIdx.x;
    const int js = bid & 1, it = (bid >> 1) & 63, b = bid >> 7;
    const int i0 = it * 16, jb = js * 512;
    const int t = threadIdx.x, w = t >> 6, l = t & 63;
    const int lg = l >> 4, l16 = l & 15;

    // stage q tile: [8h][16i][64c] bf16
    {
        int h = t >> 6, i = (t >> 2) & 15, c = (t & 3) * 16;
        const short8* src = reinterpret_cast<const short8*>(
            qhg + (((size_t)(b * 8 + h) * 1024 + i0 + i) << 6) + c);
        *reinterpret_cast<short8*>(&q1[h][i][c])     = src[0];
        *reinterpret_cast<short8*>(&q1[h][i][c + 8]) = src[1];
    }

    float mrow[4];
    #pragma unroll
    for (int r = 0; r < 4; r++) mrow[r] = mask[b * 1024 + i0 + lg * 4 + r];

    f32x4 x1[4];
    #pragma unroll
    for (int cs = 0; cs < 4; cs++) x1[cs] = 0.0f;
    f32x4 x2[2][4];
    #pragma unroll
    for (int il = 0; il < 2; il++)
        #pragma unroll
        for (int cg = 0; cg < 4; cg++) x2[il][cg] = 0.0f;
    float lsum[4] = {0.f, 0.f, 0.f, 0.f};

    const unsigned short* khb = khg + ((size_t)(b * 8 + w) << 16);
    const unsigned short* vtb = vtg + ((size_t)(b * 8 + w) << 16);
    const float* rpbb = rpb + ((size_t)(b * 1024 + i0) << 16);

    float4 pf[16];
    issue_rpb(rpbb, jb, t, pf);                 // prologue prefetch

    for (int jt = 0; jt < 16; ++jt) {
        const int j0 = jb + jt * 32;
        __syncthreads();                         // barA: prev rpb_s readers done
        // ---- write prefetched tile (vmcnt drain is automatic on first use) ----
        #pragma unroll
        for (int itr = 0; itr < 8; ++itr) {
            int flat = (itr * 512 + t) * 8;
            int i = flat >> 11, j = (flat >> 6) & 31, c = flat & 63;
            float4 ua = pf[itr * 2], ub = pf[itr * 2 + 1];
            short8 pk;
            pk[0] = (short)f2b(ua.x); pk[1] = (short)f2b(ua.y);
            pk[2] = (short)f2b(ua.z); pk[3] = (short)f2b(ua.w);
            pk[4] = (short)f2b(ub.x); pk[5] = (short)f2b(ub.y);
            pk[6] = (short)f2b(ub.z); pk[7] = (short)f2b(ub.w);
            *reinterpret_cast<short8*>(&rpb_s[i][j][c]) = pk;
        }
        if (t < 32) mj_s[t] = mask[b * 1024 + j0 + t];
        if (jt < 15) issue_rpb(rpbb, j0 + 32, t, pf);   // loads fly during compute
        __syncthreads();                         // barB: tile staged

        // ---- S1 = QK^T : D[16i x 16j] x 2 jsub, K=64 ----
        f32x4 C1[2]; C1[0] = 0.0f; C1[1] = 0.0f;
        short8 a1[2];
        a1[0] = *reinterpret_cast<const short8*>(&q1[w][l16][8 * lg]);
        a1[1] = *reinterpret_cast<const short8*>(&q1[w][l16][32 + 8 * lg]);
        #pragma unroll
        for (int ch = 0; ch < 2; ++ch) {
            #pragma unroll
            for (int jsub = 0; jsub < 2; ++jsub) {
                short8 kb = *reinterpret_cast<const short8*>(
                    khb + (((size_t)(j0 + jsub * 16 + l16)) << 6) + ch * 32 + 8 * lg);
                C1[jsub] = __builtin_amdgcn_mfma_f32_16x16x32_bf16(a1[ch], kb, C1[jsub], 0, 0, 0);
            }
        }

        // ---- S2^T = rpb(A) @ q(B) : D[j x h], all frags contiguous b128 ----
        #pragma unroll
        for (int il = 0; il < 2; ++il) {
            int i = 2 * w + il;
            f32x4 D2[2]; D2[0] = 0.0f; D2[1] = 0.0f;
            #pragma unroll
            for (int ch = 0; ch < 2; ++ch) {
                short8 bq = *reinterpret_cast<const short8*>(
                    &q1[l16 & 7][i][ch * 32 + 8 * lg]);   // B[k=c][n=h] (cols 8-15 dup)
                #pragma unroll
                for (int jsub = 0; jsub < 2; ++jsub) {
                    short8 ar = *reinterpret_cast<const short8*>(
                        &rpb_s[i][jsub * 16 + l16][ch * 32 + 8 * lg]);  // A[row=j][k=c]
                    D2[jsub] = __builtin_amdgcn_mfma_f32_16x16x32_bf16(ar, bq, D2[jsub], 0, 0, 0);
                }
            }
            if (l16 < 8) {                        // D: row=j=4lg+r, col=h=l16
                #pragma unroll
                for (int jsub = 0; jsub < 2; ++jsub)
                    #pragma unroll
                    for (int r = 0; r < 4; ++r)
                        S2s[i][l16][jsub * 16 + 4 * lg + r] = D2[jsub][r];
            }
        }
        __syncthreads();                         // barC: S2 ready

        // ---- P = exp(S1 + S2 + pairmask) ----
        #pragma unroll
        for (int jsub = 0; jsub < 2; ++jsub) {
            float mj = mj_s[jsub * 16 + l16];
            #pragma unroll
            for (int r = 0; r < 4; ++r) {
                int ir = lg * 4 + r;
                float mi = mrow[r];
                float pm = (fmaxf(mi, mj) < 0.f) ? 0.f : fminf(mi, mj);
                float s = C1[jsub][r] + S2s[ir][w][jsub * 16 + l16] + pm;
                float p = __expf(s);              // bounded logits; -1e4 -> 0
                lsum[r] += p;
                P[w][ir][jsub * 16 + l16] = f2b(p);
            }
        }
        __syncthreads();                         // barD: P ready

        // ---- X1 += P @ vhT : D[16i x 64c] ----
        short8 pa = *reinterpret_cast<const short8*>(&P[w][l16][8 * lg]);
        #pragma unroll
        for (int cs = 0; cs < 4; ++cs) {
            short8 vb = *reinterpret_cast<const short8*>(
                vtb + ((size_t)(cs * 16 + l16) << 10) + j0 + 8 * lg);
            x1[cs] = __builtin_amdgcn_mfma_f32_16x16x32_bf16(pa, vb, x1[cs], 0, 0, 0);
        }
        // ---- X2 += P(A) @ rpb(B) : per i, D[8h x 16c], K=32j ----
        #pragma unroll
        for (int il = 0; il < 2; ++il) {
            int i = 2 * w + il;
            short8 pa2 = *reinterpret_cast<const short8*>(&P[l16 & 7][i][8 * lg]);
            #pragma unroll
            for (int cg = 0; cg < 4; ++cg) {
                short8 bb;                        // B[k=j=8lg+e][n=c=cg*16+l16]
                #pragma unroll
                for (int e = 0; e < 8; ++e)
                    bb[e] = (short)rpb_s[i][8 * lg + e][cg * 16 + l16];
                x2[il][cg] = __builtin_amdgcn_mfma_f32_16x16x32_bf16(pa2, bb, x2[il][cg], 0, 0, 0);
            }
        }
    }

    // reduce lsum over the 16 j-lanes
    #pragma unroll
    for (int r = 0; r < 4; ++r) {
        float v = lsum[r];
        v += __shfl_xor(v, 1, 64); v += __shfl_xor(v, 2, 64);
        v += __shfl_xor(v, 4, 64); v += __shfl_xor(v, 8, 64);
        lsum[r] = v;
    }

    __syncthreads();   // all rpb_s reads done; reuse rpb_s as x2 redistribute buf
    float* x2s = reinterpret_cast<float*>(&rpb_s[0][0][0]);   // [16i][8h][64c] f32
    if (lg < 2) {      // valid D rows h = 4*lg + r in 0..7
        #pragma unroll
        for (int il = 0; il < 2; ++il)
            #pragma unroll
            for (int cg = 0; cg < 4; ++cg)
                #pragma unroll
                for (int r = 0; r < 4; ++r)
                    x2s[((2 * w + il) * 8 + 4 * lg + r) * 64 + cg * 16 + l16] =
                        x2[il][cg][r];
    }
    __syncthreads();

    // output: unnormalized x1+x2 partials and lsum per jsplit
    #pragma unroll
    for (int cs = 0; cs < 4; ++cs)
        #pragma unroll
        for (int r = 0; r < 4; ++r) {
            int ir = lg * 4 + r;
            float val = x1[cs][r] + x2s[(ir * 8 + w) * 64 + cs * 16 + l16];
            xpart[((size_t)js << 20) + ((size_t)(b * 1024 + i0 + ir)) * 512
                  + w * 64 + cs * 16 + l16] = val;
        }
    if (l16 == 0) {
        #pragma unroll
        for (int r = 0; r < 4; ++r)
            lsump[((size_t)js << 14) + (b * 8 + w) * 1024 + i0 + lg * 4 + r] = lsum[r];
    }
}

// ---------------------------------------------------------------------------
__global__ __launch_bounds__(256) void combine(
    const float* __restrict__ xpart, const float* __restrict__ lsump,
    float* __restrict__ xb)
{
    int idx4 = blockIdx.x * 256 + threadIdx.x;     // 262144 threads x float4
    size_t base = (size_t)idx4 * 4;
    int row = (int)(base >> 9), col = (int)(base & 511);
    int bb = row >> 10, n = row & 1023, h = col >> 6;
    float ax = 0.f, ay = 0.f, az = 0.f, aw = 0.f, ls = 0.f;
    #pragma unroll
    for (int js = 0; js < 2; ++js) {
        float4 v = *reinterpret_cast<const float4*>(xpart + ((size_t)js << 20) + base);
        ax += v.x; ay += v.y; az += v.z; aw += v.w;
        ls += lsump[(js << 14) + (bb * 8 + h) * 1024 + n];
    }
    float inv = 1.f / ls;
    float4 o; o.x = ax * inv; o.y = ay * inv; o.z = az * inv; o.w = aw * inv;
    *reinterpret_cast<float4*>(xb + base) = o;
}

// ---------------------------------------------------------------------------
extern "C" void kernel_launch(void* const* d_in, const int* in_sizes, int n_in,
                              void* d_out, int out_size, void* d_ws, size_t ws_size,
                              hipStream_t stream)
{
    (void)in_sizes; (void)n_in; (void)out_size; (void)ws_size;
    const float* q    = (const float*)d_in[0];
    const float* k    = (const float*)d_in[1];
    const float* v    = (const float*)d_in[2];
    const float* rpb  = (const float*)d_in[3];
    const float* mask = (const float*)d_in[4];
    const float* Wq   = (const float*)d_in[5];
    const float* Wk   = (const float*)d_in[6];
    const float* Wv   = (const float*)d_in[7];
    const float* Wp   = (const float*)d_in[8];
    const float* bp   = (const float*)d_in[9];
    float* out = (float*)d_out;

    unsigned short* qhb = (unsigned short*)d_ws;     // bf16 [2,8,1024,64]
    unsigned short* khb = qhb + 1048576;
    unsigned short* vtb = khb + 1048576;             // bf16 [2,8,64,1024]
    float* xpart = (float*)(vtb + 1048576);          // [2][2048][512]
    float* lsump = xpart + 2097152;                  // [2][16][1024]
    float* xb    = lsump + 32768;                    // [2048][512]

    dim3 gg(32, 8, 1);
    gemm512<0><<<gg, 256, 0, stream>>>(q, Wq, nullptr, nullptr, qhb, 0.125f);
    gemm512<0><<<gg, 256, 0, stream>>>(k, Wk, nullptr, nullptr, khb, 1.0f);
    gemm512<2><<<gg, 256, 0, stream>>>(v, Wv, nullptr, nullptr, vtb, 1.0f);

    attn_mfma<<<256, 512, 0, stream>>>(qhb, khb, vtb, rpb, mask, xpart, lsump);

    combine<<<1024, 256, 0, stream>>>(xpart, lsump, xb);

    gemm512<1><<<gg, 256, 0, stream>>>(xb, Wp, bp, out, nullptr, 1.0f);
}